// Round 1
// baseline (334.426 us; speedup 1.0000x reference)
//
#include <hip/hip_runtime.h>
#include <math.h>

// Net_17025250361809: fused Catan-GNN.
// Kernel A (conv_kernel): 1 block = 1 graph (54 nodes, 144 edges), 128 threads.
//   - stage x, edges, W1(stacked rel|root), W2 into LDS
//   - scatter-add agg1 (LDS atomics), h1 = relu([agg1|x] @ W1 + b1) with
//     per-thread W column in 32 VGPRs (K=32 GEMM)
//   - layer2 reordered: p2 = h1@W2_rel, r2 = h1@W2_root computed per node
//     FIRST, then 4-dim messages aggregated (16x less scatter work)
//   - tiny global MLP folded in (threads 0..15), writes cat[B][232]
// Kernel B (out_kernel): 16 graphs/block, 256 threads; O1_W reads amortized
//   16x (else ~1 GB L2 traffic). relu(cat@O1+b) -> sigmoid(@O2+b) -> out[B].

#define B_GR 8192
#define NNODE 54
#define EPG 144
#define CATD 232
#define ETOT (B_GR*EPG)

__global__ __launch_bounds__(128) void conv_kernel(
    const float* __restrict__ x, const int* __restrict__ ei,
    const float* __restrict__ ea, const float* __restrict__ gf,
    const float* __restrict__ W1rel, const float* __restrict__ b1,
    const float* __restrict__ W1root,
    const float* __restrict__ W2rel, const float* __restrict__ b2,
    const float* __restrict__ W2root,
    const float* __restrict__ G1W, const float* __restrict__ G1b,
    const float* __restrict__ G2W, const float* __restrict__ G2b,
    const float* __restrict__ G3W, const float* __restrict__ G3b,
    float* __restrict__ cat)
{
    __shared__ __align__(16) float sW1[32*64];   // rows 0-15: W1rel, 16-31: W1root
    __shared__ float sb1[64];
    __shared__ float sW2[64*8];                  // [d][j]: j 0-3 rel, 4-7 root
    __shared__ float sb2[4];
    __shared__ __align__(16) float scat[54*32];  // [n][k]: k 0-15 agg1, 16-31 x
    __shared__ __align__(16) float sh1[54*68];   // padded stride 68 (bank spread)
    __shared__ float spr[54*8];                  // [n][j]: j 0-3 p2, 4-7 r2
    __shared__ float sagg2[54*4];
    __shared__ int   ssrc[EPG];
    __shared__ int   sdst[EPG];
    __shared__ float sattr[EPG];
    __shared__ float sg1[8], sg2[8];

    const int tid = threadIdx.x;
    const int g = blockIdx.x;
    const int nbase = g * NNODE;

    // ---- stage weights + graph data ----
    for (int i = tid; i < 16*64; i += 128) sW1[i] = W1rel[i];
    for (int i = tid; i < 16*64; i += 128) sW1[16*64 + i] = W1root[i];
    if (tid < 64) sb1[tid] = b1[tid];
    for (int i = tid; i < 64*4; i += 128) {
        int d = i >> 2, j = i & 3;
        sW2[d*8 + j]     = W2rel[i];
        sW2[d*8 + 4 + j] = W2root[i];
    }
    if (tid < 4) sb2[tid] = b2[tid];
    for (int i = tid; i < NNODE*16; i += 128) {
        int n = i >> 4, k = i & 15;
        scat[n*32 + 16 + k] = x[(size_t)(nbase + n)*16 + k];
        scat[n*32 + k] = 0.f;
    }
    for (int e = tid; e < EPG; e += 128) {
        ssrc[e]  = ei[(size_t)g*EPG + e] - nbase;
        sdst[e]  = ei[(size_t)ETOT + (size_t)g*EPG + e] - nbase;
        sattr[e] = ea[(size_t)g*EPG + e];
    }
    __syncthreads();

    // ---- scatter-add layer-1 messages (16 dims/edge) + g1 ----
    for (int i = tid; i < EPG*16; i += 128) {
        int e = i >> 4, k = i & 15;
        atomicAdd(&scat[sdst[e]*32 + k], scat[ssrc[e]*32 + 16 + k] * sattr[e]);
    }
    if (tid < 8) {
        float a = G1b[tid];
        #pragma unroll
        for (int k = 0; k < 16; k++) a += gf[(size_t)g*16 + k] * G1W[k*8 + tid];
        sg1[tid] = fmaxf(a, 0.f);
    }
    __syncthreads();

    // ---- h1 = relu([agg1|x] @ [W1rel;W1root] + b1), K=32 ----
    {
        const int d = tid & 63, wv = tid >> 6;
        float wreg[32];
        #pragma unroll
        for (int k = 0; k < 32; k++) wreg[k] = sW1[k*64 + d];
        const float bias = sb1[d];
        for (int n = wv; n < NNODE; n += 2) {
            const float4* rp = (const float4*)&scat[n*32];
            float acc = bias;
            #pragma unroll
            for (int q = 0; q < 8; q++) {
                float4 v = rp[q];
                acc += v.x*wreg[q*4+0] + v.y*wreg[q*4+1]
                     + v.z*wreg[q*4+2] + v.w*wreg[q*4+3];
            }
            sh1[n*68 + d] = fmaxf(acc, 0.f);
        }
    }
    if (tid < 8) {
        float a = G2b[tid];
        #pragma unroll
        for (int k = 0; k < 8; k++) a += sg1[k] * G2W[k*8 + tid];
        sg2[tid] = fmaxf(a, 0.f);
    }
    __syncthreads();

    // ---- p2 = h1@W2rel, r2 = h1@W2root (per node, pre-aggregation) ----
    for (int i = tid; i < NNODE*8; i += 128) {
        int n = i >> 3, j = i & 7;
        const float4* hp = (const float4*)&sh1[n*68];
        float acc = 0.f;
        #pragma unroll
        for (int q = 0; q < 16; q++) {
            float4 v = hp[q];
            acc += v.x*sW2[(q*4+0)*8 + j] + v.y*sW2[(q*4+1)*8 + j]
                 + v.z*sW2[(q*4+2)*8 + j] + v.w*sW2[(q*4+3)*8 + j];
        }
        spr[i] = acc;
    }
    for (int i = tid; i < NNODE*4; i += 128) sagg2[i] = 0.f;
    if (tid < 16) {
        float a = G3b[tid];
        #pragma unroll
        for (int k = 0; k < 8; k++) a += sg2[k] * G3W[k*16 + tid];
        cat[(size_t)g*CATD + 216 + tid] = fmaxf(a, 0.f);
    }
    __syncthreads();

    // ---- scatter-add layer-2 messages (4 dims/edge) ----
    for (int i = tid; i < EPG*4; i += 128) {
        int e = i >> 2, j = i & 3;
        atomicAdd(&sagg2[sdst[e]*4 + j], spr[ssrc[e]*8 + j] * sattr[e]);
    }
    __syncthreads();

    // ---- h2 = relu(agg2 + r2 + b2) -> embeds ----
    for (int i = tid; i < NNODE*4; i += 128) {
        int n = i >> 2, j = i & 3;
        cat[(size_t)g*CATD + i] = fmaxf(sagg2[i] + spr[n*8 + 4 + j] + sb2[j], 0.f);
    }
}

__global__ __launch_bounds__(256) void out_kernel(
    const float* __restrict__ cat, const float* __restrict__ O1W,
    const float* __restrict__ O1b, const float* __restrict__ O2W,
    const float* __restrict__ O2b, float* __restrict__ out)
{
    __shared__ __align__(16) float semb[16*232];
    __shared__ float sout1[16*132];   // stride 132 -> 2-way banks on reduce
    __shared__ float sO1b[128];
    __shared__ float sO2w[128];

    const int tid = threadIdx.x;
    const size_t gbase = (size_t)blockIdx.x * 16;

    for (int i = tid; i < 16*CATD; i += 256) semb[i] = cat[gbase*CATD + i];
    if (tid < 128) { sO1b[tid] = O1b[tid]; sO2w[tid] = O2W[tid]; }
    __syncthreads();

    const int o = tid & 127, gs = tid >> 7;   // gs in {0,1}: 8 graphs each
    float acc[8];
    #pragma unroll
    for (int i = 0; i < 8; i++) acc[i] = sO1b[o];
    const float* eb = &semb[(gs*8)*CATD];
    for (int k = 0; k < CATD; k += 4) {
        float w0 = O1W[(size_t)(k+0)*128 + o];
        float w1 = O1W[(size_t)(k+1)*128 + o];
        float w2 = O1W[(size_t)(k+2)*128 + o];
        float w3 = O1W[(size_t)(k+3)*128 + o];
        #pragma unroll
        for (int i = 0; i < 8; i++) {
            float4 v = *(const float4*)&eb[i*CATD + k];
            acc[i] += v.x*w0 + v.y*w1 + v.z*w2 + v.w*w3;
        }
    }
    #pragma unroll
    for (int i = 0; i < 8; i++) sout1[(gs*8 + i)*132 + o] = fmaxf(acc[i], 0.f);
    __syncthreads();

    if (tid < 16) {
        float a = O2b[0];
        const float* r = &sout1[tid*132];
        for (int oo = 0; oo < 128; oo++) a += r[oo] * sO2w[oo];
        out[gbase + tid] = 1.f / (1.f + expf(-a));
    }
}

extern "C" void kernel_launch(void* const* d_in, const int* in_sizes, int n_in,
                              void* d_out, int out_size, void* d_ws, size_t ws_size,
                              hipStream_t stream) {
    const float* x      = (const float*)d_in[0];
    const int*   ei     = (const int*)d_in[1];
    const float* ea     = (const float*)d_in[2];
    const float* gf     = (const float*)d_in[3];
    const float* W1rel  = (const float*)d_in[4];
    const float* b1     = (const float*)d_in[5];
    const float* W1root = (const float*)d_in[6];
    const float* W2rel  = (const float*)d_in[7];
    const float* b2     = (const float*)d_in[8];
    const float* W2root = (const float*)d_in[9];
    const float* G1W    = (const float*)d_in[10];
    const float* G1b    = (const float*)d_in[11];
    const float* G2W    = (const float*)d_in[12];
    const float* G2b    = (const float*)d_in[13];
    const float* G3W    = (const float*)d_in[14];
    const float* G3b    = (const float*)d_in[15];
    const float* O1W    = (const float*)d_in[16];
    const float* O1b    = (const float*)d_in[17];
    const float* O2W    = (const float*)d_in[18];
    const float* O2b    = (const float*)d_in[19];
    float* out = (float*)d_out;
    float* cat = (float*)d_ws;   // [B][232] fp32 = 7.6 MB

    conv_kernel<<<dim3(B_GR), dim3(128), 0, stream>>>(
        x, ei, ea, gf, W1rel, b1, W1root, W2rel, b2, W2root,
        G1W, G1b, G2W, G2b, G3W, G3b, cat);
    out_kernel<<<dim3(B_GR/16), dim3(256), 0, stream>>>(
        cat, O1W, O1b, O2W, O2b, out);
}

// Round 3
// 194.963 us; speedup vs baseline: 1.7153x; 1.7153x over previous
//
#include <hip/hip_runtime.h>
#include <math.h>

// Net_17025250361809 round 3: wave-per-graph conv (round-2 structure, staging
// bugfix: W1 transpose loop bound was 64*32 -> OOB reads of W1rel and LDS row
// overruns corrupting W1root/bias; now 64*16).
// conv_kernel: block = 512 thr = 8 waves = 8 graphs. lane = node (54<=64).
//   x-row + agg in VGPRs; per-wave CSR (count -> shfl-scan -> place) replaces
//   atomic scatter; layer1->layer2 fused per d (h1 never stored); weight
//   reads in d-loop are wave-uniform -> LDS broadcast, conflict-free.
//   LDS ~78KB/block -> 2 blocks/CU = 16 waves/CU.
// out_kernel: 8 graphs/block, 1024 blocks.

#define B_GR 8192
#define NNODE 54
#define EPG 144
#define CATD 232
#define ETOT (B_GR*EPG)
#define WPB 8          // waves (=graphs) per conv block
#define XS 20          // x_s row stride (floats): 80B, 16B-aligned
#define PS 12          // p2_s row stride: 48B, 16B-aligned

__global__ __launch_bounds__(512, 4) void conv_kernel(
    const float* __restrict__ x, const int* __restrict__ ei,
    const float* __restrict__ ea, const float* __restrict__ gf,
    const float* __restrict__ W1rel, const float* __restrict__ b1,
    const float* __restrict__ W1root,
    const float* __restrict__ W2rel, const float* __restrict__ b2,
    const float* __restrict__ W2root,
    const float* __restrict__ G1W, const float* __restrict__ G1b,
    const float* __restrict__ G2W, const float* __restrict__ G2b,
    const float* __restrict__ G3W, const float* __restrict__ G3b,
    float* __restrict__ cat)
{
    __shared__ __align__(16) float sW1t[64*36];      // [d][k0..15=rel,16..31=root,32=b1]
    __shared__ __align__(16) float sW2[64*8];        // [d][j: 0-3 rel, 4-7 root]
    __shared__ float sb2[4];
    __shared__ __align__(16) float x_s[WPB][NNODE*XS];
    __shared__ __align__(16) float p2_s[WPB][NNODE*PS];
    __shared__ int   ssrc[WPB][EPG];
    __shared__ float sw_ [WPB][EPG];
    __shared__ int   scur[WPB][56];

    const int tid = threadIdx.x;
    const int wg  = tid >> 6;          // local graph
    const int ln  = tid & 63;          // lane = node
    const int g   = blockIdx.x * WPB + wg;
    const int nbase = g * NNODE;

    // ---- cooperative weight staging (once per block) ----
    for (int i = tid; i < 64*16; i += 512) {
        int d = i & 63, k = i >> 6;    // k in 0..15
        sW1t[d*36 + k]      = W1rel[k*64 + d];
        sW1t[d*36 + 16 + k] = W1root[k*64 + d];
    }
    if (tid < 64) sW1t[tid*36 + 32] = b1[tid];
    for (int i = tid; i < 64*4; i += 512) {
        int d = i >> 2, j = i & 3;
        sW2[d*8 + j]     = W2rel[i];
        sW2[d*8 + 4 + j] = W2root[i];
    }
    if (tid < 4) sb2[tid] = b2[tid];

    // ---- wave-local staging: x row -> regs + LDS ----
    float4 xr[4];
    if (ln < NNODE) {
        const float4* xp = (const float4*)(x + (size_t)(nbase + ln) * 16);
        #pragma unroll
        for (int q = 0; q < 4; q++) {
            xr[q] = xp[q];
            *(float4*)&x_s[wg][ln*XS + q*4] = xr[q];
        }
    }
    // ---- edges: <=3 per lane, kept in regs ----
    int e_src[3], e_dst[3]; float e_w[3];
    #pragma unroll
    for (int r = 0; r < 3; r++) {
        int e = ln + r*64;
        if (e < EPG) {
            e_src[r] = ei[(size_t)g*EPG + e] - nbase;
            e_dst[r] = ei[(size_t)ETOT + (size_t)g*EPG + e] - nbase;
            e_w[r]   = ea[(size_t)g*EPG + e];
        } else e_dst[r] = -1;
    }
    // ---- CSR build (wave-local; DS ops from one wave are FIFO-ordered) ----
    if (ln < NNODE) scur[wg][ln] = 0;
    __builtin_amdgcn_wave_barrier();
    #pragma unroll
    for (int r = 0; r < 3; r++)
        if (e_dst[r] >= 0) atomicAdd(&scur[wg][e_dst[r]], 1);
    __builtin_amdgcn_wave_barrier();
    int c = (ln < NNODE) ? scur[wg][ln] : 0;
    int s = c;                                   // inclusive shuffle scan
    #pragma unroll
    for (int off = 1; off < 64; off <<= 1) {
        int t = __shfl_up(s, off);
        if (ln >= off) s += t;
    }
    const int deg = c, base = s - c;             // per-lane CSR bounds in regs
    if (ln < NNODE) scur[wg][ln] = base;
    __builtin_amdgcn_wave_barrier();
    #pragma unroll
    for (int r = 0; r < 3; r++)
        if (e_dst[r] >= 0) {
            int pos = atomicAdd(&scur[wg][e_dst[r]], 1);
            ssrc[wg][pos] = e_src[r];
            sw_ [wg][pos] = e_w[r];
        }

    // ---- global MLP (no LDS; overlaps with other waves' staging) ----
    {
        float g1v = 0.f;
        if (ln < 8) {
            float a = G1b[ln];
            #pragma unroll
            for (int k = 0; k < 16; k++) a += gf[(size_t)g*16 + k] * G1W[k*8 + ln];
            g1v = fmaxf(a, 0.f);
        }
        float a2 = (ln < 8) ? G2b[ln] : 0.f;
        #pragma unroll
        for (int k = 0; k < 8; k++) a2 += __shfl(g1v, k) * G2W[k*8 + (ln & 7)];
        float g2v = fmaxf(a2, 0.f);
        float a3 = (ln < 16) ? G3b[ln] : 0.f;
        #pragma unroll
        for (int k = 0; k < 8; k++) a3 += __shfl(g2v, k) * G3W[k*16 + (ln & 15)];
        if (ln < 16) cat[(size_t)g*CATD + 216 + ln] = fmaxf(a3, 0.f);
    }
    __syncthreads();

    // ---- layer-1 aggregation: gather via CSR into regs ----
    float4 a4[4] = {{0,0,0,0},{0,0,0,0},{0,0,0,0},{0,0,0,0}};
    for (int e2 = 0; e2 < deg; e2++) {
        int sv = ssrc[wg][base + e2];
        float w = sw_[wg][base + e2];
        const float4* rp = (const float4*)&x_s[wg][sv*XS];
        #pragma unroll
        for (int q = 0; q < 4; q++) {
            float4 v = rp[q];
            a4[q].x += w*v.x; a4[q].y += w*v.y; a4[q].z += w*v.z; a4[q].w += w*v.w;
        }
    }

    // ---- fused layer1 -> layer2 projections (h1 never stored) ----
    float4 pr0 = {0,0,0,0}, pr1 = {0,0,0,0};     // p2 (rel-proj), r2 (root-proj)
    for (int d = 0; d < 64; d++) {
        const float4* wp = (const float4*)&sW1t[d*36];   // wave-uniform -> broadcast
        float h = sW1t[d*36 + 32];
        #pragma unroll
        for (int q = 0; q < 4; q++) {
            float4 wv = wp[q];
            h += a4[q].x*wv.x + a4[q].y*wv.y + a4[q].z*wv.z + a4[q].w*wv.w;
        }
        #pragma unroll
        for (int q = 0; q < 4; q++) {
            float4 wv = wp[4+q];
            h += xr[q].x*wv.x + xr[q].y*wv.y + xr[q].z*wv.z + xr[q].w*wv.w;
        }
        h = fmaxf(h, 0.f);
        float4 u0 = *(const float4*)&sW2[d*8];
        float4 u1 = *(const float4*)&sW2[d*8 + 4];
        pr0.x += h*u0.x; pr0.y += h*u0.y; pr0.z += h*u0.z; pr0.w += h*u0.w;
        pr1.x += h*u1.x; pr1.y += h*u1.y; pr1.z += h*u1.z; pr1.w += h*u1.w;
    }
    if (ln < NNODE) *(float4*)&p2_s[wg][ln*PS] = pr0;
    __syncthreads();

    // ---- layer-2 aggregation + epilogue ----
    if (ln < NNODE) {
        float4 a2 = {0,0,0,0};
        for (int e2 = 0; e2 < deg; e2++) {
            int sv = ssrc[wg][base + e2];
            float w = sw_[wg][base + e2];
            float4 p = *(const float4*)&p2_s[wg][sv*PS];
            a2.x += w*p.x; a2.y += w*p.y; a2.z += w*p.z; a2.w += w*p.w;
        }
        float4 o;
        o.x = fmaxf(a2.x + pr1.x + sb2[0], 0.f);
        o.y = fmaxf(a2.y + pr1.y + sb2[1], 0.f);
        o.z = fmaxf(a2.z + pr1.z + sb2[2], 0.f);
        o.w = fmaxf(a2.w + pr1.w + sb2[3], 0.f);
        *(float4*)&cat[(size_t)g*CATD + ln*4] = o;
    }
}

__global__ __launch_bounds__(256) void out_kernel(
    const float* __restrict__ cat, const float* __restrict__ O1W,
    const float* __restrict__ O1b, const float* __restrict__ O2W,
    const float* __restrict__ O2b, float* __restrict__ out)
{
    __shared__ __align__(16) float semb[8*CATD];
    __shared__ float sout1[8*132];
    __shared__ float sO1b[128];
    __shared__ float sO2w[128];

    const int tid = threadIdx.x;
    const size_t gbase = (size_t)blockIdx.x * 8;

    for (int i = tid; i < 8*CATD; i += 256) semb[i] = cat[gbase*CATD + i];
    if (tid < 128) { sO1b[tid] = O1b[tid]; sO2w[tid] = O2W[tid]; }
    __syncthreads();

    const int o = tid & 127, gs = tid >> 7;     // gs in {0,1}: 4 graphs each
    float acc[4];
    #pragma unroll
    for (int i = 0; i < 4; i++) acc[i] = sO1b[o];
    const float* eb = &semb[(gs*4)*CATD];
    for (int k = 0; k < CATD; k += 4) {
        float w0 = O1W[(size_t)(k+0)*128 + o];
        float w1 = O1W[(size_t)(k+1)*128 + o];
        float w2 = O1W[(size_t)(k+2)*128 + o];
        float w3 = O1W[(size_t)(k+3)*128 + o];
        #pragma unroll
        for (int i = 0; i < 4; i++) {
            float4 v = *(const float4*)&eb[i*CATD + k];
            acc[i] += v.x*w0 + v.y*w1 + v.z*w2 + v.w*w3;
        }
    }
    #pragma unroll
    for (int i = 0; i < 4; i++) sout1[(gs*4 + i)*132 + o] = fmaxf(acc[i], 0.f);
    __syncthreads();

    if (tid < 8) {
        float a = O2b[0];
        const float* r = &sout1[tid*132];
        for (int oo = 0; oo < 128; oo++) a += r[oo] * sO2w[oo];
        out[gbase + tid] = 1.f / (1.f + expf(-a));
    }
}

extern "C" void kernel_launch(void* const* d_in, const int* in_sizes, int n_in,
                              void* d_out, int out_size, void* d_ws, size_t ws_size,
                              hipStream_t stream) {
    const float* x      = (const float*)d_in[0];
    const int*   ei     = (const int*)d_in[1];
    const float* ea     = (const float*)d_in[2];
    const float* gf     = (const float*)d_in[3];
    const float* W1rel  = (const float*)d_in[4];
    const float* b1     = (const float*)d_in[5];
    const float* W1root = (const float*)d_in[6];
    const float* W2rel  = (const float*)d_in[7];
    const float* b2     = (const float*)d_in[8];
    const float* W2root = (const float*)d_in[9];
    const float* G1W    = (const float*)d_in[10];
    const float* G1b    = (const float*)d_in[11];
    const float* G2W    = (const float*)d_in[12];
    const float* G2b    = (const float*)d_in[13];
    const float* G3W    = (const float*)d_in[14];
    const float* G3b    = (const float*)d_in[15];
    const float* O1W    = (const float*)d_in[16];
    const float* O1b    = (const float*)d_in[17];
    const float* O2W    = (const float*)d_in[18];
    const float* O2b    = (const float*)d_in[19];
    float* out = (float*)d_out;
    float* cat = (float*)d_ws;   // [B][232] fp32 = 7.6 MB

    conv_kernel<<<dim3(B_GR/WPB), dim3(512), 0, stream>>>(
        x, ei, ea, gf, W1rel, b1, W1root, W2rel, b2, W2root,
        G1W, G1b, G2W, G2b, G3W, G3b, cat);
    out_kernel<<<dim3(B_GR/8), dim3(256), 0, stream>>>(
        cat, O1W, O1b, O2W, O2b, out);
}

// Round 10
// 181.675 us; speedup vs baseline: 1.8408x; 1.0731x over previous
//
#include <hip/hip_runtime.h>
#include <math.h>

// Net_17025250361809 round 4 (sixth resubmit after GPU acquisition timeouts).
// prepack_kernel: weights -> wpack[64][48] rows (W1rel^T | W1root^T | b1 | W2rel | W2root)
//   so conv's d-loop reads weights with wave-uniform addresses -> s_load
//   (SMEM pipe + SGPR fma operands), removing 640 ds_read_b128/graph.
// conv_kernel: wave-per-graph, NO __syncthreads (all LDS is wave-private),
//   CSR packed as int2 (one ds_read_b64 per edge).
// out_kernel: 16 graphs/block, acc[8] ILP, parallel tail reduce (8 lanes/graph).

#define B_GR 8192
#define NNODE 54
#define EPG 144
#define CATD 232
#define ETOT (B_GR*EPG)
#define WPB 8          // waves (=graphs) per conv block
#define XS 20          // x_s row stride (floats)
#define PS 12          // p2_s row stride (floats)
#define WROW 48        // wpack row stride (floats), 192B = 64B-aligned

__global__ __launch_bounds__(64) void prepack_kernel(
    const float* __restrict__ W1rel, const float* __restrict__ b1,
    const float* __restrict__ W1root,
    const float* __restrict__ W2rel, const float* __restrict__ W2root,
    float* __restrict__ wpack)
{
    const int d = threadIdx.x;   // 64 threads, one per hidden dim
    float* r = wpack + d * WROW;
    #pragma unroll
    for (int k = 0; k < 16; k++) {
        r[k]      = W1rel[k*64 + d];
        r[16 + k] = W1root[k*64 + d];
    }
    r[32] = b1[d];
    #pragma unroll
    for (int j = 0; j < 4; j++) {
        r[33 + j] = W2rel[d*4 + j];
        r[37 + j] = W2root[d*4 + j];
    }
    #pragma unroll
    for (int j = 41; j < WROW; j++) r[j] = 0.f;
}

__global__ __launch_bounds__(512, 4) void conv_kernel(
    const float* __restrict__ x, const int* __restrict__ ei,
    const float* __restrict__ ea, const float* __restrict__ gf,
    const float* __restrict__ wpack, const float* __restrict__ b2,
    const float* __restrict__ G1W, const float* __restrict__ G1b,
    const float* __restrict__ G2W, const float* __restrict__ G2b,
    const float* __restrict__ G3W, const float* __restrict__ G3b,
    float* __restrict__ cat)
{
    __shared__ __align__(16) float x_s[WPB][NNODE*XS];
    __shared__ __align__(16) float p2_s[WPB][NNODE*PS];
    __shared__ __align__(16) int2  sedge[WPB][EPG];   // (src, w-bits)
    __shared__ int scur[WPB][56];

    const int tid = threadIdx.x;
    const int wg  = tid >> 6;          // local graph
    const int ln  = tid & 63;          // lane = node
    const int g   = blockIdx.x * WPB + wg;
    const int nbase = g * NNODE;

    // ---- wave-local staging: x row -> regs + LDS ----
    float4 xr[4];
    if (ln < NNODE) {
        const float4* xp = (const float4*)(x + (size_t)(nbase + ln) * 16);
        #pragma unroll
        for (int q = 0; q < 4; q++) {
            xr[q] = xp[q];
            *(float4*)&x_s[wg][ln*XS + q*4] = xr[q];
        }
    }
    // ---- edges: <=3 per lane, kept in regs ----
    int e_src[3], e_dst[3]; float e_w[3];
    #pragma unroll
    for (int r = 0; r < 3; r++) {
        int e = ln + r*64;
        if (e < EPG) {
            e_src[r] = ei[(size_t)g*EPG + e] - nbase;
            e_dst[r] = ei[(size_t)ETOT + (size_t)g*EPG + e] - nbase;
            e_w[r]   = ea[(size_t)g*EPG + e];
        } else e_dst[r] = -1;
    }
    // ---- CSR build (wave-local; DS ops from one wave are FIFO-ordered) ----
    if (ln < 56) scur[wg][ln] = 0;
    __builtin_amdgcn_wave_barrier();
    #pragma unroll
    for (int r = 0; r < 3; r++)
        if (e_dst[r] >= 0) atomicAdd(&scur[wg][e_dst[r]], 1);
    __builtin_amdgcn_wave_barrier();
    int c = (ln < NNODE) ? scur[wg][ln] : 0;
    int s = c;                                   // inclusive shuffle scan
    #pragma unroll
    for (int off = 1; off < 64; off <<= 1) {
        int t = __shfl_up(s, off);
        if (ln >= off) s += t;
    }
    const int deg = c, base = s - c;
    if (ln < NNODE) scur[wg][ln] = base;
    __builtin_amdgcn_wave_barrier();
    #pragma unroll
    for (int r = 0; r < 3; r++)
        if (e_dst[r] >= 0) {
            int pos = atomicAdd(&scur[wg][e_dst[r]], 1);
            sedge[wg][pos] = make_int2(e_src[r], __float_as_int(e_w[r]));
        }

    // ---- global MLP (registers + shuffles only) ----
    {
        float g1v = 0.f;
        if (ln < 8) {
            float a = G1b[ln];
            #pragma unroll
            for (int k = 0; k < 16; k++) a += gf[(size_t)g*16 + k] * G1W[k*8 + ln];
            g1v = fmaxf(a, 0.f);
        }
        float a2 = (ln < 8) ? G2b[ln] : 0.f;
        #pragma unroll
        for (int k = 0; k < 8; k++) a2 += __shfl(g1v, k) * G2W[k*8 + (ln & 7)];
        float g2v = fmaxf(a2, 0.f);
        float a3 = (ln < 16) ? G3b[ln] : 0.f;
        #pragma unroll
        for (int k = 0; k < 8; k++) a3 += __shfl(g2v, k) * G3W[k*16 + (ln & 15)];
        if (ln < 16) cat[(size_t)g*CATD + 216 + ln] = fmaxf(a3, 0.f);
    }
    __builtin_amdgcn_wave_barrier();

    // ---- layer-1 aggregation: gather via CSR into regs ----
    float4 a4[4] = {{0,0,0,0},{0,0,0,0},{0,0,0,0},{0,0,0,0}};
    for (int e2 = 0; e2 < deg; e2++) {
        int2 se = sedge[wg][base + e2];
        float w = __int_as_float(se.y);
        const float4* rp = (const float4*)&x_s[wg][se.x*XS];
        #pragma unroll
        for (int q = 0; q < 4; q++) {
            float4 v = rp[q];
            a4[q].x += w*v.x; a4[q].y += w*v.y; a4[q].z += w*v.z; a4[q].w += w*v.w;
        }
    }

    // ---- fused layer1 -> layer2 projections; weights via s_load ----
    float4 pr0 = {0,0,0,0}, pr1 = {0,0,0,0};
    #pragma unroll 2
    for (int d = 0; d < 64; d++) {
        const float* wr = wpack + d*WROW;        // wave-uniform -> SMEM
        float h = wr[32];
        h += a4[0].x*wr[0]  + a4[0].y*wr[1]  + a4[0].z*wr[2]  + a4[0].w*wr[3];
        h += a4[1].x*wr[4]  + a4[1].y*wr[5]  + a4[1].z*wr[6]  + a4[1].w*wr[7];
        h += a4[2].x*wr[8]  + a4[2].y*wr[9]  + a4[2].z*wr[10] + a4[2].w*wr[11];
        h += a4[3].x*wr[12] + a4[3].y*wr[13] + a4[3].z*wr[14] + a4[3].w*wr[15];
        h += xr[0].x*wr[16] + xr[0].y*wr[17] + xr[0].z*wr[18] + xr[0].w*wr[19];
        h += xr[1].x*wr[20] + xr[1].y*wr[21] + xr[1].z*wr[22] + xr[1].w*wr[23];
        h += xr[2].x*wr[24] + xr[2].y*wr[25] + xr[2].z*wr[26] + xr[2].w*wr[27];
        h += xr[3].x*wr[28] + xr[3].y*wr[29] + xr[3].z*wr[30] + xr[3].w*wr[31];
        h = fmaxf(h, 0.f);
        pr0.x += h*wr[33]; pr0.y += h*wr[34]; pr0.z += h*wr[35]; pr0.w += h*wr[36];
        pr1.x += h*wr[37]; pr1.y += h*wr[38]; pr1.z += h*wr[39]; pr1.w += h*wr[40];
    }
    if (ln < NNODE) *(float4*)&p2_s[wg][ln*PS] = pr0;
    __builtin_amdgcn_wave_barrier();

    // ---- layer-2 aggregation + epilogue ----
    if (ln < NNODE) {
        float4 a2 = {0,0,0,0};
        for (int e2 = 0; e2 < deg; e2++) {
            int2 se = sedge[wg][base + e2];
            float w = __int_as_float(se.y);
            float4 p = *(const float4*)&p2_s[wg][se.x*PS];
            a2.x += w*p.x; a2.y += w*p.y; a2.z += w*p.z; a2.w += w*p.w;
        }
        float4 o;
        o.x = fmaxf(a2.x + pr1.x + b2[0], 0.f);
        o.y = fmaxf(a2.y + pr1.y + b2[1], 0.f);
        o.z = fmaxf(a2.z + pr1.z + b2[2], 0.f);
        o.w = fmaxf(a2.w + pr1.w + b2[3], 0.f);
        *(float4*)&cat[(size_t)g*CATD + ln*4] = o;
    }
}

#define OG 16   // graphs per out block

__global__ __launch_bounds__(256) void out_kernel(
    const float* __restrict__ cat, const float* __restrict__ O1W,
    const float* __restrict__ O1b, const float* __restrict__ O2W,
    const float* __restrict__ O2b, float* __restrict__ out)
{
    __shared__ __align__(16) float semb[OG*CATD];
    __shared__ float sout1[OG*132];
    __shared__ float sO2w[128];

    const int tid = threadIdx.x;
    const size_t gbase = (size_t)blockIdx.x * OG;

    for (int i = tid; i < OG*CATD; i += 256) semb[i] = cat[gbase*CATD + i];
    if (tid < 128) sO2w[tid] = O2W[tid];
    __syncthreads();

    const int o = tid & 127, gs = tid >> 7;     // gs in {0,1}: 8 graphs each
    {
        const float bias = O1b[o];
        float acc[8];
        #pragma unroll
        for (int i = 0; i < 8; i++) acc[i] = bias;
        const float* eb = &semb[(gs*8)*CATD];
        for (int k = 0; k < CATD; k += 4) {
            float w0 = O1W[(size_t)(k+0)*128 + o];
            float w1 = O1W[(size_t)(k+1)*128 + o];
            float w2 = O1W[(size_t)(k+2)*128 + o];
            float w3 = O1W[(size_t)(k+3)*128 + o];
            #pragma unroll
            for (int i = 0; i < 8; i++) {
                float4 v = *(const float4*)&eb[i*CATD + k];
                acc[i] += v.x*w0 + v.y*w1 + v.z*w2 + v.w*w3;
            }
        }
        #pragma unroll
        for (int i = 0; i < 8; i++) sout1[(gs*8 + i)*132 + o] = fmaxf(acc[i], 0.f);
    }
    __syncthreads();

    // parallel tail: 8 lanes per graph
    float a = 0.f;
    const int gg = tid >> 3, t8 = tid & 7;
    if (tid < 128) {
        const float* r = &sout1[gg*132];
        #pragma unroll
        for (int oo = t8; oo < 128; oo += 8) a += r[oo] * sO2w[oo];
    }
    a += __shfl_xor(a, 1);
    a += __shfl_xor(a, 2);
    a += __shfl_xor(a, 4);
    if (tid < 128 && t8 == 0)
        out[gbase + gg] = 1.f / (1.f + expf(-(a + O2b[0])));
}

extern "C" void kernel_launch(void* const* d_in, const int* in_sizes, int n_in,
                              void* d_out, int out_size, void* d_ws, size_t ws_size,
                              hipStream_t stream) {
    const float* x      = (const float*)d_in[0];
    const int*   ei     = (const int*)d_in[1];
    const float* ea     = (const float*)d_in[2];
    const float* gf     = (const float*)d_in[3];
    const float* W1rel  = (const float*)d_in[4];
    const float* b1     = (const float*)d_in[5];
    const float* W1root = (const float*)d_in[6];
    const float* W2rel  = (const float*)d_in[7];
    const float* b2     = (const float*)d_in[8];
    const float* W2root = (const float*)d_in[9];
    const float* G1W    = (const float*)d_in[10];
    const float* G1b    = (const float*)d_in[11];
    const float* G2W    = (const float*)d_in[12];
    const float* G2b    = (const float*)d_in[13];
    const float* G3W    = (const float*)d_in[14];
    const float* G3b    = (const float*)d_in[15];
    const float* O1W    = (const float*)d_in[16];
    const float* O1b    = (const float*)d_in[17];
    const float* O2W    = (const float*)d_in[18];
    const float* O2b    = (const float*)d_in[19];
    float* out = (float*)d_out;
    float* cat   = (float*)d_ws;                       // [B][232] fp32 = 7.60 MB
    float* wpack = (float*)((char*)d_ws + (size_t)B_GR*CATD*4);  // 64B-aligned

    prepack_kernel<<<dim3(1), dim3(64), 0, stream>>>(
        W1rel, b1, W1root, W2rel, W2root, wpack);
    conv_kernel<<<dim3(B_GR/WPB), dim3(512), 0, stream>>>(
        x, ei, ea, gf, wpack, b2,
        G1W, G1b, G2W, G2b, G3W, G3b, cat);
    out_kernel<<<dim3(B_GR/OG), dim3(256), 0, stream>>>(
        cat, O1W, O1b, O2W, O2b, out);
}